// Round 8
// baseline (864.136 us; speedup 1.0000x reference)
//
#include <hip/hip_runtime.h>
#include <hip/hip_bf16.h>
#include <stdint.h>

#define BATCH_N 65536
#define KDIM 1024
#define NTOT 1536

typedef __bf16 bf16x8 __attribute__((ext_vector_type(8)));
typedef float f32x4 __attribute__((ext_vector_type(4)));

__device__ __forceinline__ unsigned short f2bf(float f) {
    unsigned u = __builtin_bit_cast(unsigned, f);
    u += 0x7FFFu + ((u >> 16) & 1u);   // round-to-nearest-even
    return (unsigned short)(u >> 16);
}

// ---------------------------------------------------------------------------
// Kernel 1: x[b][k] = sum(node_memories[id]) + node_embedding[id][k], bf16,
// PLAIN row-major layout (GEMM now reads fragments straight from global).
// One WAVE per row; each lane owns 4 float4 chunks (full 1024 coverage).
// ---------------------------------------------------------------------------
__global__ __launch_bounds__(256) void prep_kernel(
    const int* __restrict__ ids,
    const float* __restrict__ mem,
    const float* __restrict__ emb,
    unsigned short* __restrict__ x)
{
    const int b    = blockIdx.x * 4 + (threadIdx.x >> 6);
    const int lane = threadIdx.x & 63;
    const int id   = ids[b];
    const float4* m4 = (const float4*)(mem + (size_t)id * KDIM) + lane;
    const float4* e4 = (const float4*)(emb + (size_t)id * KDIM) + lane;
    float4 v0 = m4[0];
    float4 v1 = m4[64];
    float4 v2 = m4[128];
    float4 v3 = m4[192];
    float s = (v0.x + v0.y + v0.z + v0.w) + (v1.x + v1.y + v1.z + v1.w)
            + (v2.x + v2.y + v2.z + v2.w) + (v3.x + v3.y + v3.z + v3.w);
    #pragma unroll
    for (int off = 1; off < 64; off <<= 1) s += __shfl_xor(s, off, 64);
    unsigned short* xb = x + (size_t)b * KDIM;
    #pragma unroll
    for (int q = 0; q < 4; ++q) {
        float4 e = e4[q * 64];
        ushort4 o;
        o.x = f2bf(s + e.x);
        o.y = f2bf(s + e.y);
        o.z = f2bf(s + e.z);
        o.w = f2bf(s + e.w);
        *(ushort4*)(xb + q * 256 + lane * 4) = o;
    }
}

// ---------------------------------------------------------------------------
// Kernel 2: Wt[n][k] = W_{n/512}[k][n%512] in bf16, plain n-major layout.
// ---------------------------------------------------------------------------
__global__ __launch_bounds__(256) void wconv_kernel(
    const float* __restrict__ Wq, const float* __restrict__ Ws,
    const float* __restrict__ Wk, unsigned short* __restrict__ wt)
{
    const int gt = blockIdx.x * 256 + threadIdx.x;   // 0..393215
    const int n  = gt % NTOT;
    const int kb = (gt / NTOT) * 4;
    const float* W = (n < 512) ? Wq : ((n < 1024) ? Ws : Wk);
    const int nn = n & 511;
    ushort4 o;
    o.x = f2bf(W[(size_t)(kb + 0) * 512 + nn]);
    o.y = f2bf(W[(size_t)(kb + 1) * 512 + nn]);
    o.z = f2bf(W[(size_t)(kb + 2) * 512 + nn]);
    o.w = f2bf(W[(size_t)(kb + 3) * 512 + nn]);
    *(ushort4*)(wt + (size_t)n * KDIM + kb) = o;
}

// ---------------------------------------------------------------------------
// Kernel 3: FLAT register GEMM + bias + sigmoid.  NO LDS, NO barriers, NO
// manual waitcnt -- every load is compiler-tracked global->VGPR, loaded in
// exact MFMA fragment layout (16B/lane):
//   A frag (tile kt): lane reads X[m0+wm*64+i*16+r16][kt*64+(lane>>4)*8+kk*32 ..+7]
//   B frag (tile kt): lane reads Wt[n0+wn*64+j*16+r16][same k]  (Wt is n-major)
// Register double-buffer: named sets (a0,b0)/(a1,b1), 1-tile lookahead,
// fully unrolled 16-tile K loop.  B (3 MB) is L2-resident; A panels are
// L2-hot via nt-fastest order + bijective XCD swizzle.
// 256 threads = 4 waves (2M x 2N), per-wave 64x64 output, acc 64 VGPR.
// ---------------------------------------------------------------------------
#define BM 128
#define BN 128
#define MT (BATCH_N / BM)   // 512
#define NT (NTOT / BN)      // 12
#define NWG (MT * NT)       // 6144 = 8 * 768, 768 % 12 == 0 -> bijective

__global__ __launch_bounds__(256, 2) void gemm_kernel(
    const unsigned short* __restrict__ X,    // [65536][1024] bf16, plain
    const unsigned short* __restrict__ Wt,   // [1536][1024]  bf16, plain
    const float* __restrict__ bq, const float* __restrict__ bs,
    const float* __restrict__ bk, float* __restrict__ out)
{
    const int tid  = threadIdx.x;
    const int xcd  = blockIdx.x & 7;
    const int idx  = blockIdx.x >> 3;
    const int wgid = xcd * (NWG / 8) + idx;
    const int nt   = wgid % NT;              // n fastest: A-panel L2 reuse
    const int mt   = wgid / NT;
    const int m0   = mt * BM;
    const int n0   = nt * BN;
    const int wid  = tid >> 6;
    const int lane = tid & 63;
    const int wm   = wid >> 1;               // 0..1
    const int wn   = wid & 1;                // 0..1
    const int r16  = lane & 15;
    const int kc8  = (lane >> 4) << 3;       // k elem offset {0,8,16,24}

    // per-lane fragment base pointers (16B-aligned)
    const unsigned short* pA = X  + (size_t)(m0 + wm * 64 + r16) * KDIM + kc8;
    const unsigned short* pB = Wt + (size_t)(n0 + wn * 64 + r16) * KDIM + kc8;

    f32x4 acc[4][4];
    #pragma unroll
    for (int i = 0; i < 4; i++)
        #pragma unroll
        for (int j = 0; j < 4; j++)
            acc[i][j] = f32x4{0.f, 0.f, 0.f, 0.f};

    bf16x8 a0[4][2], b0[4][2], a1[4][2], b1[4][2];

#define LOADA(SET, kt) do {                                                     \
    _Pragma("unroll")                                                            \
    for (int i = 0; i < 4; ++i)                                                  \
        _Pragma("unroll")                                                        \
        for (int kk = 0; kk < 2; ++kk)                                           \
            SET[i][kk] = *(const bf16x8*)(pA + (size_t)i * 16 * KDIM             \
                                             + (kt) * 64 + kk * 32);             \
} while (0)
#define LOADB(SET, kt) do {                                                     \
    _Pragma("unroll")                                                            \
    for (int j = 0; j < 4; ++j)                                                  \
        _Pragma("unroll")                                                        \
        for (int kk = 0; kk < 2; ++kk)                                           \
            SET[j][kk] = *(const bf16x8*)(pB + (size_t)j * 16 * KDIM             \
                                             + (kt) * 64 + kk * 32);             \
} while (0)
#define MM(SA, SB) do {                                                         \
    _Pragma("unroll")                                                            \
    for (int i = 0; i < 4; ++i)                                                  \
        _Pragma("unroll")                                                        \
        for (int j = 0; j < 4; ++j)                                              \
            _Pragma("unroll")                                                    \
            for (int kk = 0; kk < 2; ++kk)                                       \
                acc[i][j] = __builtin_amdgcn_mfma_f32_16x16x32_bf16(             \
                    SA[i][kk], SB[j][kk], acc[i][j], 0, 0, 0);                   \
} while (0)

    LOADA(a0, 0); LOADB(b0, 0);
    #pragma unroll
    for (int t = 0; t < 16; t += 2) {
        if (t + 1 < 16) { LOADA(a1, t + 1); LOADB(b1, t + 1); }
        MM(a0, b0);
        if (t + 2 < 16) { LOADA(a0, t + 2); LOADB(b0, t + 2); }
        if (t + 1 < 16) { MM(a1, b1); }
    }

    // ---- epilogue: bias + sigmoid, nontemporal fp32 stores ----
    // C/D layout: col=lane&15, row=(lane>>4)*4+reg  [m89/m91]
    const int grp = n0 >> 9;                        // 0=q, 1=s, 2=k
    const float* bias = (grp == 0) ? bq : ((grp == 1) ? bs : bk);
    float* obase = out + (size_t)grp * ((size_t)BATCH_N * 512);
    const int nb = n0 & 511;
    #pragma unroll
    for (int j = 0; j < 4; ++j) {
        const int col = nb + wn * 64 + j * 16 + r16;
        const float bv = bias[col];
        #pragma unroll
        for (int i = 0; i < 4; ++i) {
            const int rbase = m0 + wm * 64 + i * 16 + ((lane >> 4) << 2);
            #pragma unroll
            for (int r = 0; r < 4; ++r) {
                float v = acc[i][j][r] + bv;
                v = 1.0f / (1.0f + __expf(-v));
                __builtin_nontemporal_store(v, &obase[(size_t)(rbase + r) * 512 + col]);
            }
        }
    }
#undef LOADA
#undef LOADB
#undef MM
}

extern "C" void kernel_launch(void* const* d_in, const int* in_sizes, int n_in,
                              void* d_out, int out_size, void* d_ws, size_t ws_size,
                              hipStream_t stream) {
    const int*   ids = (const int*)d_in[0];
    const float* mem = (const float*)d_in[1];
    const float* emb = (const float*)d_in[2];
    const float* Wq  = (const float*)d_in[3];
    const float* bq  = (const float*)d_in[4];
    const float* Ws  = (const float*)d_in[5];
    const float* bs  = (const float*)d_in[6];
    const float* Wk  = (const float*)d_in[7];
    const float* bk  = (const float*)d_in[8];
    float* out = (float*)d_out;

    unsigned short* x  = (unsigned short*)d_ws;              // 65536*1024 bf16 = 128 MiB
    unsigned short* wt = x + (size_t)BATCH_N * KDIM;         // 1536*1024  bf16 = 3 MiB

    hipLaunchKernelGGL(wconv_kernel, dim3(NTOT), dim3(256), 0, stream, Wq, Ws, Wk, wt);
    hipLaunchKernelGGL(prep_kernel, dim3(BATCH_N / 4), dim3(256), 0, stream, ids, mem, emb, x);
    hipLaunchKernelGGL(gemm_kernel, dim3(NWG), dim3(256), 0, stream,
                       x, wt, bq, bs, bk, out);
}